// Round 11
// baseline (198.903 us; speedup 1.0000x reference)
//
#include <hip/hip_runtime.h>
#include <stdint.h>

typedef unsigned long long u64;
typedef unsigned int u32;
typedef unsigned short u16;

#define NBINS 512
#define CAP 512          // max candidates per head (count-cap rule)
#define POOLCAP 2048     // >= W*CAP margin: pool provably holds all heads' candidates
#define LOG_CUT (-64.0f)
#define NTA 256
#define NTB 512

// Bucket = pure monotone function of the sort key bits (nn = 1-ue, f32 in [0,1)).
// d = bits(1.0f) - bits(nn) grows as nn shrinks (usage grows); fine-log of d with
// 16 sub-bins/octave. Convention: HIGH bucket = small usage = candidate side.
// No transcendentals; bit-exact purity (no straddling of near-equal keys).
__device__ __forceinline__ int bucket_of(u32 nnbits) {
    u32 d = 0x3F800000u - nnbits;
    if (d == 0u) d = 1u;
    const int e = 31 - __builtin_clz(d);                    // 0..29
    const u32 sub = (e >= 4) ? ((d >> (e - 4)) & 15u) : ((d << (4 - e)) & 15u);
    return (NBINS - 1) - ((e << 4) | (int)sub);             // in [32, 511]
}

// ---------------- Kernel A: pure streaming (round-4-validated, untouched) ----------------
// usage = (prev + (1-prev)*(1-prod_w(1-ww))) * prod_r(1-fg*rw), bit-exact f32;
// zero-fills alloc. No LDS, no hist: runs at ~90% of the 604MB roofline.
template <int TW, int TR>
__global__ __launch_bounds__(NTA)
void phaseA_kernel(const float* __restrict__ ww, const float* __restrict__ fg,
                   const float* __restrict__ rw, const float* __restrict__ prev,
                   float* __restrict__ out_usage, float* __restrict__ out_alloc,
                   int B, int W, int R, int M)
{
    const int Wl = TW > 0 ? TW : W;
    const int Rl = TR > 0 ? TR : R;
    const int g4 = M >> 2;
    const long long total = (long long)B * g4;
    const long long stride = (long long)gridDim.x * blockDim.x;
    for (long long g = (long long)blockIdx.x * blockDim.x + threadIdx.x; g < total; g += stride) {
        const int b = (int)(g / g4);
        const int m = ((int)(g % g4)) << 2;
        const size_t bM = (size_t)b * M + m;
        const float4 pv = *(const float4*)(prev + bM);
        float pr0 = 1.f, pr1 = 1.f, pr2 = 1.f, pr3 = 1.f;
        #pragma unroll
        for (int w = 0; w < Wl; ++w) {
            const float4 a = *(const float4*)(ww + ((size_t)b * Wl + w) * M + m);
            pr0 *= (1.0f - a.x); pr1 *= (1.0f - a.y);
            pr2 *= (1.0f - a.z); pr3 *= (1.0f - a.w);
        }
        float u0 = pv.x + (1.0f - pv.x) * (1.0f - pr0);
        float u1 = pv.y + (1.0f - pv.y) * (1.0f - pr1);
        float u2 = pv.z + (1.0f - pv.z) * (1.0f - pr2);
        float u3 = pv.w + (1.0f - pv.w) * (1.0f - pr3);
        float f0 = 1.f, f1 = 1.f, f2 = 1.f, f3 = 1.f;
        #pragma unroll
        for (int r = 0; r < Rl; ++r) {
            const float fr = fg[(size_t)b * Rl + r];
            const float4 a = *(const float4*)(rw + ((size_t)b * Rl + r) * M + m);
            f0 *= (1.0f - fr * a.x); f1 *= (1.0f - fr * a.y);
            f2 *= (1.0f - fr * a.z); f3 *= (1.0f - fr * a.w);
        }
        float4 uo;
        uo.x = u0 * f0; uo.y = u1 * f1; uo.z = u2 * f2; uo.w = u3 * f3;
        *(float4*)(out_usage + bM) = uo;
        const float4 z = make_float4(0.f, 0.f, 0.f, 0.f);
        #pragma unroll
        for (int w = 0; w < Wl; ++w)
            *(float4*)(out_alloc + ((size_t)b * Wl + w) * M + m) = z;
    }
}

// ---------------- Kernel B: one-read register-cached pool allocation ----------------
// Loads its row's usage ONCE into registers; count-hist via bucket_of (no log2f);
// pc scan; compact pool from registers; heads touch only the <=2048-element pool
// (validated machinery: pool hist w/ exact log-mass -> suffix scan -> bucket-grouped
// rank == full key-order rank -> sparse scatter + in-pool usage update).
template <int GPT>   // GPT = M/(4*NTB); 0 = generic (global re-reads)
__global__ __launch_bounds__(NTB, 4)
void phaseB_kernel(const float* __restrict__ wgt,
                   const float* __restrict__ usage_in,   // [B,M]
                   float* __restrict__ out_alloc,        // [B,W,M] pre-zeroed by A
                   int B, int W, int M)
{
    __shared__ float poolU[POOLCAP];
    __shared__ u16   poolIdx[POOLCAP];
    __shared__ float poolLg[POOLCAP];
    __shared__ u32   hC[NBINS];
    __shared__ float hL[NBINS];
    __shared__ u32   cntAb[NBINS];
    __shared__ float masAb[NBINS];
    __shared__ u32   grpFill[NBINS];
    __shared__ u64   candKey[CAP];
    __shared__ float candLg[CAP];
    __shared__ u16   candPos[CAP];
    __shared__ u16   candBkt[CAP];
    __shared__ u32   tc[8];
    __shared__ float twv[8];
    __shared__ int   misc[4];       // [0]=pool count, [1]=xs, [2]=xc, [3]=pc

    const int b = blockIdx.x;
    const int t = threadIdx.x;
    const int lane = t & 63;
    const int wid = t >> 6;

    const float C1 = (float)(1.0 - 1e-6);
    const float CE = 1e-6f;
    const float* U = usage_in + (size_t)b * M;

    hC[t] = 0u;
    if (t == 0) { misc[0] = 0; misc[3] = NBINS; }
    __syncthreads();

    // ---- load usage into registers + count histogram (bit-trick buckets) ----
    float4 rv[GPT > 0 ? GPT : 1];
    if (GPT > 0) {
        #pragma unroll
        for (int k = 0; k < (GPT > 0 ? GPT : 1); ++k)
            rv[k] = *(const float4*)(U + (t + k * NTB) * 4);
        #pragma unroll
        for (int k = 0; k < (GPT > 0 ? GPT : 1); ++k) {
            const float ua[4] = {rv[k].x, rv[k].y, rv[k].z, rv[k].w};
            #pragma unroll
            for (int j = 0; j < 4; ++j) {
                const float nn = 1.0f - (CE + C1 * ua[j]);
                atomicAdd(&hC[bucket_of(__float_as_uint(nn))], 1u);
            }
        }
    } else {
        for (int m = t; m < M; m += NTB) {
            const float nn = 1.0f - (CE + C1 * U[m]);
            atomicAdd(&hC[bucket_of(__float_as_uint(nn))], 1u);
        }
    }
    __syncthreads();

    // ---- pool cut: min x with suffix-count <= POOLCAP (thread t owns x=NBINS-1-t) ----
    {
        const int x = NBINS - 1 - t;
        u32 sc = hC[x];
        #pragma unroll
        for (int off = 1; off < 64; off <<= 1) {
            const u32 oc = __shfl_up(sc, off);
            if (lane >= off) sc += oc;
        }
        if (lane == 63) tc[wid] = sc;
        __syncthreads();
        u32 ac = 0;
        for (int q = 0; q < wid; ++q) ac += tc[q];
        sc += ac;
        if (sc <= (u32)POOLCAP) atomicMin(&misc[3], x);
    }
    __syncthreads();
    const int pc = misc[3];

    // ---- pool compact from registers (bkt >= pc); set-deterministic ----
    if (GPT > 0) {
        #pragma unroll
        for (int k = 0; k < (GPT > 0 ? GPT : 1); ++k) {
            const float ua[4] = {rv[k].x, rv[k].y, rv[k].z, rv[k].w};
            #pragma unroll
            for (int j = 0; j < 4; ++j) {
                const int m = (t + k * NTB) * 4 + j;
                const float u = ua[j];
                const float nn = 1.0f - (CE + C1 * u);
                const int bkt = bucket_of(__float_as_uint(nn));
                const bool pred = (bkt >= pc) && (pc < NBINS);
                const u64 mask = __ballot(pred);
                const int cnt = __popcll(mask);
                if (cnt) {
                    int base = 0;
                    if (lane == 0) base = atomicAdd(&misc[0], cnt);
                    base = __shfl(base, 0);
                    if (pred) {
                        const int pos = base + __popcll(mask & ((1ull << lane) - 1));
                        if (pos < POOLCAP) { poolU[pos] = u; poolIdx[pos] = (u16)m; }
                    }
                }
            }
        }
    } else {
        for (int m = t; m < M; m += NTB) {
            const float u = U[m];
            const float nn = 1.0f - (CE + C1 * u);
            const int bkt = bucket_of(__float_as_uint(nn));
            const bool pred = (bkt >= pc) && (pc < NBINS);
            const u64 mask = __ballot(pred);
            const int cnt = __popcll(mask);
            if (cnt) {
                int base = 0;
                if (lane == 0) base = atomicAdd(&misc[0], cnt);
                base = __shfl(base, 0);
                if (pred) {
                    const int pos = base + __popcll(mask & ((1ull << lane) - 1));
                    if (pos < POOLCAP) { poolU[pos] = u; poolIdx[pos] = (u16)m; }
                }
            }
        }
    }
    __syncthreads();
    int P = misc[0]; if (P > POOLCAP) P = POOLCAP;

    // ---- heads: pool-only (validated machinery, bucket_of substituted) ----
    for (int i = 0; i < W; ++i) {
        const float wgi = wgt[(size_t)b * W + i];
        float* orow = out_alloc + ((size_t)b * W + i) * M;

        hC[t] = 0u; hL[t] = 0.0f; grpFill[t] = 0u;
        if (t < CAP) candKey[t] = ~0ull;
        if (t == 0) { misc[1] = -1; misc[2] = NBINS; }
        __syncthreads();

        // pool-local histogram with exact per-bucket log-mass (log2f on pool only)
        for (int p = t; p < P; p += NTB) {
            const float u = poolU[p];
            const float nn = 1.0f - (CE + C1 * u);
            const float lg = __log2f(1.0f - nn);          // log2(ue_b), ref's cumprod term
            poolLg[p] = lg;
            const int bkt = bucket_of(__float_as_uint(nn));
            atomicAdd(&hC[bkt], 1u);
            atomicAdd(&hL[bkt], lg);
        }
        __syncthreads();

        // suffix scan: exact counts/mass; xs/xc gated to x >= pc (pool-hist ==
        // full-row hist there; head cuts provably never fall below pc)
        {
            const int x = NBINS - 1 - t;
            const u32 c = hC[x];
            const float w0 = hL[x];
            u32 sc = c; float sw = w0;
            #pragma unroll
            for (int off = 1; off < 64; off <<= 1) {
                const u32  oc = __shfl_up(sc, off);
                const float ow = __shfl_up(sw, off);
                if (lane >= off) { sc += oc; sw += ow; }
            }
            if (lane == 63) { tc[wid] = sc; twv[wid] = sw; }
            __syncthreads();
            u32 ac = 0; float aw = 0.f;
            for (int q = 0; q < wid; ++q) { ac += tc[q]; aw += twv[q]; }
            sc += ac; sw += aw;
            cntAb[x] = sc - c;
            masAb[x] = sw - w0;
            if (x >= pc) {
                if (sw <= LOG_CUT)  atomicMax(&misc[1], x);   // mass cut
                if (sc <= (u32)CAP) atomicMin(&misc[2], x);   // count cap
            }
        }
        __syncthreads();
        const int xs = misc[1], xc = misc[2];
        const int cut = xs > xc ? xs : xc;
        int K = 0;
        if (cut < NBINS) K = (int)(cntAb[cut] + hC[cut]);
        if (K > CAP) K = CAP;

        // candidate select -> bucket-grouped slots (slot = cntAb[bkt] + fill)
        for (int p = t; p < P; p += NTB) {
            const float u = poolU[p];
            const float nn = 1.0f - (CE + C1 * u);
            const int bkt = bucket_of(__float_as_uint(nn));
            if (cut < NBINS && bkt >= cut) {
                const u64 key = (((u64)(~__float_as_uint(nn))) << 16) | (u64)poolIdx[p];
                const int slot = (int)cntAb[bkt] + (int)atomicAdd(&grpFill[bkt], 1u);
                if (slot < CAP) {
                    candKey[slot] = key; candLg[slot] = poolLg[p];
                    candPos[slot] = (u16)p; candBkt[slot] = (u16)bkt;
                }
            }
        }
        __syncthreads();

        // grouped rank == full key-order rank (bucket monotone-pure in key);
        // alloc = nonusage * exp2(S), S = mass above + same-bucket smaller keys
        if (t < K) {
            const u64 key = candKey[t];
            const int bkt = (int)candBkt[t];
            float S = masAb[bkt];
            const int g0 = (int)cntAb[bkt];
            const int gn = (int)hC[bkt];
            for (int j = g0; j < g0 + gn; ++j) {
                if (candKey[j] < key) S += candLg[j];
            }
            const float nn = __uint_as_float(~((u32)(key >> 16)));
            const int idx = (int)(key & 0xFFFFull);
            const float al = nn * __builtin_exp2f(S);
            if (al != 0.0f) {
                orow[idx] = al;                       // row pre-zeroed by kernel A
                const int p = (int)candPos[t];
                const float u0 = poolU[p];
                poolU[p] = u0 + ((1.0f - u0) * wgi) * al;   // ref's usage update
            }
        }
        __syncthreads();
    }
}

extern "C" void kernel_launch(void* const* d_in, const int* in_sizes, int n_in,
                              void* d_out, int out_size, void* d_ws, size_t ws_size,
                              hipStream_t stream) {
    const float* ww   = (const float*)d_in[0];
    const float* fg   = (const float*)d_in[1];
    const float* rw   = (const float*)d_in[2];
    const float* prev = (const float*)d_in[3];
    const float* wgt  = (const float*)d_in[4];
    const int BWM = in_sizes[0];
    const int BR  = in_sizes[1];
    const int BM  = in_sizes[3];
    const int BW  = in_sizes[4];
    const int M = BWM / BW;
    const int B = BM / M;
    const int W = BW / B;
    const int R = BR / B;

    float* out_usage = (float*)d_out;
    float* out_alloc = out_usage + (size_t)BM;

    // Kernel A: pure streaming (grid-stride, high occupancy)
    const long long granules = (long long)B * (M >> 2);
    int blocks = (int)((granules + NTA - 1) / NTA);
    if (blocks > 2048) blocks = 2048;
    if (W == 4 && R == 8) {
        hipLaunchKernelGGL((phaseA_kernel<4, 8>), dim3(blocks), dim3(NTA), 0, stream,
                           ww, fg, rw, prev, out_usage, out_alloc, B, W, R, M);
    } else {
        hipLaunchKernelGGL((phaseA_kernel<0, 0>), dim3(blocks), dim3(NTA), 0, stream,
                           ww, fg, rw, prev, out_usage, out_alloc, B, W, R, M);
    }

    // Kernel B: one-read pool allocation
    if (M == NTB * 4 * 8) {
        hipLaunchKernelGGL((phaseB_kernel<8>), dim3(B), dim3(NTB), 0, stream,
                           wgt, out_usage, out_alloc, B, W, M);
    } else {
        hipLaunchKernelGGL((phaseB_kernel<0>), dim3(B), dim3(NTB), 0, stream,
                           wgt, out_usage, out_alloc, B, W, M);
    }
}

// Round 12
// 156.990 us; speedup vs baseline: 1.2670x; 1.2670x over previous
//
#include <hip/hip_runtime.h>
#include <stdint.h>

typedef unsigned long long u64;
typedef unsigned int u32;

#define NBINS 512
#define CAP 512
#define LOG_CUT (-64.0f)
#define LOG_SCALE 20.0f
#define NT 1024          // 16 waves/block; 512 blocks -> 2 blocks/CU -> 32 waves/CU

// Round-5 structure (best measured: 163us) widened to NT=1024 for full occupancy.
// One workgroup per batch row.
// Phase S: interleaved-load streaming -> usage (bit-exact f32) -> LDS uS + global;
//          zero-fill alloc rows. NO register cache (R9's spill lesson): uS in LDS.
// Phase H (x W heads): log-histogram -> parallel suffix scan -> ballot compact ->
//          O(K^2) pairwise rank (K<=512) -> sparse scatter + LDS usage update.
// LDS: uS 64KB dyn + ~8.7KB static = 72.7KB -> exactly 2 blocks/CU.
template <int TW, int TR>
__global__ __launch_bounds__(NT, 8)   // 8 waves/SIMD -> VGPR cap 64 (loop runs at ~32)
void fused_kernel(const float* __restrict__ ww,    // [B,W,M]
                  const float* __restrict__ fg,    // [B,R]
                  const float* __restrict__ rw,    // [B,R,M]
                  const float* __restrict__ prev,  // [B,M]
                  const float* __restrict__ wgt,   // [B,W]
                  float* __restrict__ out_usage,   // [B,M]
                  float* __restrict__ out_alloc,   // [B,W,M]
                  int B, int W, int R, int M)
{
    __shared__ u64   keyS[CAP];
    __shared__ float logS[CAP];
    __shared__ u32   hC[NBINS];
    __shared__ u32   tc[16];
    __shared__ float twv[16];
    __shared__ int   misc[4];   // [0]=cand count, [1]=max xs, [2]=min xc
    extern __shared__ float uS[];                  // M floats

    const int Wl = TW > 0 ? TW : W;
    const int Rl = TR > 0 ? TR : R;
    const int b = blockIdx.x;
    const int t = threadIdx.x;
    const int lane = t & 63;
    const int wid = t >> 6;

    const float C1 = (float)(1.0 - 1e-6);
    const float CE = 1e-6f;

    // ---------------- Phase S: streaming (R5 structure verbatim) ----------------
    // usage = (prev + (1-prev)*(1-prod_w(1-ww))) * prod_r(1-fg*rw), ref f32 op order
    {
        const size_t rowOff = (size_t)b * M;
        float frs[TR > 0 ? TR : 8];
        #pragma unroll
        for (int r = 0; r < Rl; ++r) frs[r] = fg[(size_t)b * Rl + r];

        const float4 z = make_float4(0.f, 0.f, 0.f, 0.f);
        for (int m = t * 4; m < M; m += NT * 4) {
            const float4 pv = *(const float4*)(prev + rowOff + m);
            float pr0 = 1.f, pr1 = 1.f, pr2 = 1.f, pr3 = 1.f;
            #pragma unroll
            for (int w = 0; w < Wl; ++w) {
                const float4 a = *(const float4*)(ww + ((size_t)b * Wl + w) * M + m);
                pr0 *= (1.0f - a.x); pr1 *= (1.0f - a.y);
                pr2 *= (1.0f - a.z); pr3 *= (1.0f - a.w);
            }
            float u0 = pv.x + (1.0f - pv.x) * (1.0f - pr0);
            float u1 = pv.y + (1.0f - pv.y) * (1.0f - pr1);
            float u2 = pv.z + (1.0f - pv.z) * (1.0f - pr2);
            float u3 = pv.w + (1.0f - pv.w) * (1.0f - pr3);
            float f0 = 1.f, f1 = 1.f, f2 = 1.f, f3 = 1.f;
            #pragma unroll
            for (int r = 0; r < Rl; ++r) {
                const float fr = frs[r];
                const float4 a = *(const float4*)(rw + ((size_t)b * Rl + r) * M + m);
                f0 *= (1.0f - fr * a.x); f1 *= (1.0f - fr * a.y);
                f2 *= (1.0f - fr * a.z); f3 *= (1.0f - fr * a.w);
            }
            float4 uo;
            uo.x = u0 * f0; uo.y = u1 * f1; uo.z = u2 * f2; uo.w = u3 * f3;
            *(float4*)(uS + m) = uo;
            *(float4*)(out_usage + rowOff + m) = uo;
            #pragma unroll
            for (int w = 0; w < Wl; ++w)
                *(float4*)(out_alloc + ((size_t)b * Wl + w) * M + m) = z;
        }
    }

    // ---------------- Phase H: per write head (R5 machinery, NT=1024 guards) ----------------
    for (int i = 0; i < Wl; ++i) {
        const float wgi = wgt[(size_t)b * Wl + i];
        float* orow = out_alloc + ((size_t)b * Wl + i) * M;

        if (t < NBINS) hC[t] = 0u;
        if (t == 0) { misc[0] = 0; misc[1] = -1; misc[2] = NBINS; }
        __syncthreads();   // orders phase-S LDS writes / prior head updates too

        // count-only log-domain histogram: bkt = floor(-log2(ue)*20)
        for (int x = t * 4; x < M; x += NT * 4) {
            const float4 uu = *(const float4*)(uS + x);
            const float ua[4] = {uu.x, uu.y, uu.z, uu.w};
            #pragma unroll
            for (int j = 0; j < 4; ++j) {
                const float ue = CE + C1 * ua[j];
                const float lg = __log2f(ue);
                int bkt = (int)(-lg * LOG_SCALE);
                bkt = bkt < 0 ? 0 : (bkt > NBINS - 1 ? NBINS - 1 : bkt);
                atomicAdd(&hC[bkt], 1u);
            }
        }
        __syncthreads();

        // parallel suffix scan over buckets (thread t<512 owns x = NBINS-1-t):
        // Sc = suffix count; Sw = conservative log bound (bkt y => log2(ue) <= -y/20,
        // so Sw >= true sum; Sw<=LOG_CUT => true sum <= LOG_CUT)
        {
            const bool act = (t < NBINS);
            u32 sc = 0; float sw = 0.f; int x = 0;
            if (act) {
                x = NBINS - 1 - t;
                const u32 c = hC[x];
                sc = c;
                sw = -(float)x * (1.0f / LOG_SCALE) * (float)c;
                #pragma unroll
                for (int off = 1; off < 64; off <<= 1) {
                    const u32  oc = __shfl_up(sc, off);
                    const float ow = __shfl_up(sw, off);
                    if (lane >= off) { sc += oc; sw += ow; }
                }
                if (lane == 63) { tc[wid] = sc; twv[wid] = sw; }
            }
            __syncthreads();
            if (act) {
                u32 ac = 0; float aw = 0.f;
                for (int q = 0; q < wid; ++q) { ac += tc[q]; aw += twv[q]; }
                sc += ac; sw += aw;
                if (sw <= LOG_CUT) atomicMax(&misc[1], x);   // enough log-mass
                if (sc <= (u32)CAP) atomicMin(&misc[2], x);  // within count cap
            }
        }
        __syncthreads();
        const int xs = misc[1];
        const int xc = misc[2];
        const int cut = (xs > xc) ? xs : xc;

        // compact candidates (bkt >= cut), wave-aggregated counter
        // key = (~bits(1-ue) << 14) | idx: asc == nonusage desc, low-idx tiebreak
        for (int x = t; x < M; x += NT) {
            const float u = uS[x];
            const float ue = CE + C1 * u;
            const float lg = __log2f(ue);
            int bkt = (int)(-lg * LOG_SCALE);
            bkt = bkt < 0 ? 0 : (bkt > NBINS - 1 ? NBINS - 1 : bkt);
            const bool pred = (bkt >= cut) && (cut < NBINS);
            const u64 mask = __ballot(pred);
            const int cnt = __popcll(mask);
            if (cnt) {
                int base = 0;
                if (lane == 0) base = atomicAdd(&misc[0], cnt);
                base = __shfl(base, 0);
                if (pred) {
                    const int pos = base + __popcll(mask & ((1ull << lane) - 1));
                    if (pos < CAP) {
                        const float nn = 1.0f - ue;
                        keyS[pos] = (((u64)(~__float_as_uint(nn))) << 14) | (u64)(u32)x;
                        logS[pos] = lg;
                    }
                }
            }
        }
        __syncthreads();
        int K = misc[0]; if (K > CAP) K = CAP;

        // pairwise rank: S_t = sum log2(ue_k) over strictly-smaller keys;
        // alloc = nonusage * exp2(S) (abs err ~1e-3 << 2e-2 threshold)
        if (t < K) {
            const u64 mykey = keyS[t];
            float S = 0.0f;
            #pragma unroll 4
            for (int k = 0; k < K; ++k) {
                const u64 kk = keyS[k];      // LDS broadcast
                const float lg = logS[k];
                if (kk < mykey) S += lg;
            }
            const float nn = __uint_as_float(~((u32)(mykey >> 14)));
            const int idx = (int)(mykey & 0x3FFFull);
            const float al = nn * __builtin_exp2f(S);
            if (al != 0.0f) {
                orow[idx] = al;                          // row pre-zeroed in phase S
                const float u0v = uS[idx];
                uS[idx] = u0v + ((1.0f - u0v) * wgi) * al;
            }
        }
        __syncthreads();
    }
}

extern "C" void kernel_launch(void* const* d_in, const int* in_sizes, int n_in,
                              void* d_out, int out_size, void* d_ws, size_t ws_size,
                              hipStream_t stream) {
    const float* ww   = (const float*)d_in[0];
    const float* fg   = (const float*)d_in[1];
    const float* rw   = (const float*)d_in[2];
    const float* prev = (const float*)d_in[3];
    const float* wgt  = (const float*)d_in[4];
    const int BWM = in_sizes[0];
    const int BR  = in_sizes[1];
    const int BM  = in_sizes[3];
    const int BW  = in_sizes[4];
    const int M = BWM / BW;
    const int B = BM / M;
    const int W = BW / B;
    const int R = BR / B;

    float* out_usage = (float*)d_out;
    float* out_alloc = out_usage + (size_t)BM;

    const size_t smem = (size_t)M * sizeof(float);   // dynamic: uS only
    if (W == 4 && R == 8) {
        hipLaunchKernelGGL((fused_kernel<4, 8>), dim3(B), dim3(NT), smem, stream,
                           ww, fg, rw, prev, wgt, out_usage, out_alloc, B, W, R, M);
    } else {
        hipLaunchKernelGGL((fused_kernel<0, 0>), dim3(B), dim3(NT), smem, stream,
                           ww, fg, rw, prev, wgt, out_usage, out_alloc, B, W, R, M);
    }
}

// Round 14
// 149.006 us; speedup vs baseline: 1.3349x; 1.0536x over previous
//
#include <hip/hip_runtime.h>
#include <stdint.h>

typedef unsigned long long u64;
typedef unsigned int u32;
typedef float f32x4 __attribute__((ext_vector_type(4)));

#define NBINS 512
#define CAP 512
#define LOG_CUT (-64.0f)
#define NT 1024          // 16 waves/block; 512 blocks -> 2 blocks/CU -> 32 waves/CU

// Bucket = pure monotone function of sort-key bits (nn = 1-ue, f32 in [0,1]).
// d = bits(1.0f)-bits(nn) grows as usage grows; 16 sub-bins/octave of d.
// HIGH bucket = small usage = candidate side. No transcendentals.
__device__ __forceinline__ int bucket_of(u32 nnbits) {
    u32 d = 0x3F800000u - nnbits;
    if (d == 0u) d = 1u;
    const int e = 31 - __builtin_clz(d);                    // 0..29
    const u32 sub = (e >= 4) ? ((d >> (e - 4)) & 15u) : ((d << (4 - e)) & 15u);
    int v = (e << 4) | (int)sub;
    if (v > NBINS - 1) v = NBINS - 1;
    return (NBINS - 1) - v;
}

__device__ __forceinline__ void nt_store4(float* p, float4 v) {
    f32x4 nv;
    nv.x = v.x; nv.y = v.y; nv.z = v.z; nv.w = v.w;
    __builtin_nontemporal_store(nv, (f32x4*)p);
}

// R12 structure (157us best) + phase-H diet:
//  - hist built inline during S (bucket_of, cheap ALU)
//  - heads never rebuild hist: rank/update maintains hC incrementally
//  - scan mass bound = hC[x]*mB[x] (static per-bucket table)
//  - compact pass transcendental-free; log2f only for accepted candidates
//  - nontemporal output stores (don't evict inputs from L3 across replays)
// LDS: uS 64KB dyn + ~10.5KB static -> 2 blocks/CU.
template <int TW, int TR>
__global__ __launch_bounds__(NT, 8)
void fused_kernel(const float* __restrict__ ww,    // [B,W,M]
                  const float* __restrict__ fg,    // [B,R]
                  const float* __restrict__ rw,    // [B,R,M]
                  const float* __restrict__ prev,  // [B,M]
                  const float* __restrict__ wgt,   // [B,W]
                  float* __restrict__ out_usage,   // [B,M]
                  float* __restrict__ out_alloc,   // [B,W,M]
                  int B, int W, int R, int M)
{
    __shared__ u64   keyS[CAP];
    __shared__ float logS[CAP];
    __shared__ u32   hC[NBINS];     // persistent across heads (incremental)
    __shared__ float mB[NBINS];     // per-bucket upper bound of log2(ue)
    __shared__ u32   tc[16];
    __shared__ float twv[16];
    __shared__ int   misc[4];       // [0]=cand count, [1]=max xs, [2]=min xc
    extern __shared__ float uS[];   // M floats

    const int Wl = TW > 0 ? TW : W;
    const int Rl = TR > 0 ? TR : R;
    const int b = blockIdx.x;
    const int t = threadIdx.x;
    const int lane = t & 63;
    const int wid = t >> 6;

    const float C1 = (float)(1.0 - 1e-6);
    const float CE = 1e-6f;

    // init hist + mass-bound table (once)
    if (t < NBINS) {
        hC[t] = 0u;
        const int v = NBINS - 1 - t;          // (e<<4)|sub
        const int e = v >> 4;
        const u32 sub = (u32)(v & 15);
        const int sh = e >= 4 ? e - 4 : 0;
        u64 dhi64 = ((u64)(17u + sub) << sh) + 1u;   // safe upper bound of d in bucket
        u32 dhi = dhi64 > 0x3F800000ull ? 0x3F800000u : (u32)dhi64;
        const float nnlo = __uint_as_float(0x3F800000u - dhi);
        float ueub = 1.0f - nnlo;
        ueub = ueub < 1e-38f ? 1e-38f : (ueub > 0.9999999f ? 0.9999999f : ueub);
        mB[t] = __log2f(ueub);                // >= log2(ue) for bucket members (~1e-7 slack)
    }
    __syncthreads();

    // ---------------- Phase S: streaming + inline bucket hist ----------------
    // usage = (prev + (1-prev)*(1-prod_w(1-ww))) * prod_r(1-fg*rw), ref f32 op order
    {
        const size_t rowOff = (size_t)b * M;
        float frs[TR > 0 ? TR : 8];
        #pragma unroll
        for (int r = 0; r < Rl; ++r) frs[r] = fg[(size_t)b * Rl + r];

        const float4 z = make_float4(0.f, 0.f, 0.f, 0.f);
        for (int m = t * 4; m < M; m += NT * 4) {
            const float4 pv = *(const float4*)(prev + rowOff + m);
            float pr0 = 1.f, pr1 = 1.f, pr2 = 1.f, pr3 = 1.f;
            #pragma unroll
            for (int w = 0; w < Wl; ++w) {
                const float4 a = *(const float4*)(ww + ((size_t)b * Wl + w) * M + m);
                pr0 *= (1.0f - a.x); pr1 *= (1.0f - a.y);
                pr2 *= (1.0f - a.z); pr3 *= (1.0f - a.w);
            }
            float u0 = pv.x + (1.0f - pv.x) * (1.0f - pr0);
            float u1 = pv.y + (1.0f - pv.y) * (1.0f - pr1);
            float u2 = pv.z + (1.0f - pv.z) * (1.0f - pr2);
            float u3 = pv.w + (1.0f - pv.w) * (1.0f - pr3);
            float f0 = 1.f, f1 = 1.f, f2 = 1.f, f3 = 1.f;
            #pragma unroll
            for (int r = 0; r < Rl; ++r) {
                const float fr = frs[r];
                const float4 a = *(const float4*)(rw + ((size_t)b * Rl + r) * M + m);
                f0 *= (1.0f - fr * a.x); f1 *= (1.0f - fr * a.y);
                f2 *= (1.0f - fr * a.z); f3 *= (1.0f - fr * a.w);
            }
            float4 uo;
            uo.x = u0 * f0; uo.y = u1 * f1; uo.z = u2 * f2; uo.w = u3 * f3;
            *(float4*)(uS + m) = uo;
            nt_store4(out_usage + rowOff + m, uo);
            #pragma unroll
            for (int w = 0; w < Wl; ++w)
                nt_store4(out_alloc + ((size_t)b * Wl + w) * M + m, z);
            // inline hist (bucket of key bits; no transcendentals)
            const float ua[4] = {uo.x, uo.y, uo.z, uo.w};
            #pragma unroll
            for (int j = 0; j < 4; ++j) {
                const float nn = 1.0f - (CE + C1 * ua[j]);
                atomicAdd(&hC[bucket_of(__float_as_uint(nn))], 1u);
            }
        }
    }

    // ---------------- Phase H: per write head ----------------
    for (int i = 0; i < Wl; ++i) {
        const float wgi = wgt[(size_t)b * Wl + i];
        float* orow = out_alloc + ((size_t)b * Wl + i) * M;

        if (t == 0) { misc[0] = 0; misc[1] = -1; misc[2] = NBINS; }
        __syncthreads();   // orders S hist / prior-head hC+uS updates

        // suffix scan over persistent hist: count + bounded mass (hC[x]*mB[x])
        {
            const bool act = (t < NBINS);
            u32 sc = 0; float sw = 0.f; int x = 0;
            if (act) {
                x = NBINS - 1 - t;
                const u32 c = hC[x];
                sc = c;
                sw = mB[x] * (float)c;
                #pragma unroll
                for (int off = 1; off < 64; off <<= 1) {
                    const u32  oc = __shfl_up(sc, off);
                    const float ow = __shfl_up(sw, off);
                    if (lane >= off) { sc += oc; sw += ow; }
                }
                if (lane == 63) { tc[wid] = sc; twv[wid] = sw; }
            }
            __syncthreads();
            if (act) {
                u32 ac = 0; float aw = 0.f;
                for (int q = 0; q < wid; ++q) { ac += tc[q]; aw += twv[q]; }
                sc += ac; sw += aw;
                if (sw <= LOG_CUT) atomicMax(&misc[1], x);   // enough log-mass
                if (sc <= (u32)CAP) atomicMin(&misc[2], x);  // within count cap
            }
        }
        __syncthreads();
        const int xs = misc[1];
        const int xc = misc[2];
        const int cut = (xs > xc) ? xs : xc;

        // compact candidates (bkt >= cut): transcendental-free predicate;
        // log2f only for accepted. key asc == nonusage desc, low-idx tiebreak.
        for (int x = t; x < M; x += NT) {
            const float u = uS[x];
            const float ue = CE + C1 * u;
            const float nn = 1.0f - ue;
            const int bkt = bucket_of(__float_as_uint(nn));
            const bool pred = (bkt >= cut) && (cut < NBINS);
            const u64 mask = __ballot(pred);
            const int cnt = __popcll(mask);
            if (cnt) {
                int base = 0;
                if (lane == 0) base = atomicAdd(&misc[0], cnt);
                base = __shfl(base, 0);
                if (pred) {
                    const int pos = base + __popcll(mask & ((1ull << lane) - 1));
                    if (pos < CAP) {
                        keyS[pos] = (((u64)(~__float_as_uint(nn))) << 14) | (u64)(u32)x;
                        logS[pos] = __log2f(ue);
                    }
                }
            }
        }
        __syncthreads();
        int K = misc[0]; if (K > CAP) K = CAP;

        // pairwise rank: S = sum log2(ue_k) over strictly-smaller keys;
        // alloc = nn * exp2(S); update uS + incremental hist (skip on last head)
        if (t < K) {
            const u64 mykey = keyS[t];
            float S = 0.0f;
            #pragma unroll 4
            for (int k = 0; k < K; ++k) {
                const u64 kk = keyS[k];      // LDS broadcast
                const float lg = logS[k];
                if (kk < mykey) S += lg;
            }
            const u32 nnbits = ~((u32)(mykey >> 14));
            const float nn = __uint_as_float(nnbits);
            const int idx = (int)(mykey & 0x3FFFull);
            const float al = nn * __builtin_exp2f(S);
            if (al != 0.0f) {
                orow[idx] = al;                          // row pre-zeroed in phase S
                if (i + 1 < Wl) {
                    const float u0v = uS[idx];
                    const float unew = u0v + ((1.0f - u0v) * wgi) * al;
                    uS[idx] = unew;
                    const int bold = bucket_of(nnbits);
                    const float nn2 = 1.0f - (CE + C1 * unew);
                    const int bnew = bucket_of(__float_as_uint(nn2));
                    if (bnew != bold) {
                        atomicSub(&hC[bold], 1u);
                        atomicAdd(&hC[bnew], 1u);
                    }
                }
            }
        }
        __syncthreads();
    }
}

extern "C" void kernel_launch(void* const* d_in, const int* in_sizes, int n_in,
                              void* d_out, int out_size, void* d_ws, size_t ws_size,
                              hipStream_t stream) {
    const float* ww   = (const float*)d_in[0];
    const float* fg   = (const float*)d_in[1];
    const float* rw   = (const float*)d_in[2];
    const float* prev = (const float*)d_in[3];
    const float* wgt  = (const float*)d_in[4];
    const int BWM = in_sizes[0];
    const int BR  = in_sizes[1];
    const int BM  = in_sizes[3];
    const int BW  = in_sizes[4];
    const int M = BWM / BW;
    const int B = BM / M;
    const int W = BW / B;
    const int R = BR / B;

    float* out_usage = (float*)d_out;
    float* out_alloc = out_usage + (size_t)BM;

    const size_t smem = (size_t)M * sizeof(float);   // dynamic: uS only (M <= 16384: 14-bit idx)
    if (W == 4 && R == 8) {
        hipLaunchKernelGGL((fused_kernel<4, 8>), dim3(B), dim3(NT), smem, stream,
                           ww, fg, rw, prev, wgt, out_usage, out_alloc, B, W, R, M);
    } else {
        hipLaunchKernelGGL((fused_kernel<0, 0>), dim3(B), dim3(NT), smem, stream,
                           ww, fg, rw, prev, wgt, out_usage, out_alloc, B, W, R, M);
    }
}

// Round 15
// 146.402 us; speedup vs baseline: 1.3586x; 1.0178x over previous
//
#include <hip/hip_runtime.h>
#include <stdint.h>

typedef unsigned long long u64;
typedef unsigned int u32;
typedef unsigned short u16;
typedef float f32x4 __attribute__((ext_vector_type(4)));

#define NBINS 512
#define CAP 256          // per-head candidate cap; excluded alloc <= e^-1/257 ~ 1.4e-3
#define POOLCAP 2048     // >= CAP + 3*CAP bumped: pool provably holds all heads' candidates
#define LOG_CUT (-64.0f)
#define NT 1024          // 16 waves/block; 512 blocks -> 2 blocks/CU -> 32 waves/CU

// Bucket = pure monotone function of sort-key bits (nn = 1-ue, f32 in [0,1]).
// d = bits(1.0f)-bits(nn) grows as usage grows; 16 sub-bins/octave of d.
// HIGH bucket = small usage = candidate side. No transcendentals.
__device__ __forceinline__ int bucket_of(u32 nnbits) {
    u32 d = 0x3F800000u - nnbits;
    if (d == 0u) d = 1u;
    const int e = 31 - __builtin_clz(d);                    // 0..29
    const u32 sub = (e >= 4) ? ((d >> (e - 4)) & 15u) : ((d << (4 - e)) & 15u);
    int v = (e << 4) | (int)sub;
    if (v > NBINS - 1) v = NBINS - 1;
    return (NBINS - 1) - v;
}

__device__ __forceinline__ void nt_store4(float* p, float4 v) {
    f32x4 nv;
    nv.x = v.x; nv.y = v.y; nv.z = v.z; nv.w = v.w;
    __builtin_nontemporal_store(nv, (f32x4*)p);
}

// R14 structure (149us best) + pool-once phase H:
//  - S: stream, inline bit-hist, REGULAR usage store (L2-hot), nt alloc stores,
//       NO uS LDS write
//  - pool built once by re-reading out_usage from L2 (one float4 pass)
//  - heads: scan (persistent incremental hist) -> 2-iter pool compact ->
//           O(K^2) rank (K<=256) -> sparse scatter + pool/hist update
// LDS ~33KB static, no dynamic.
template <int TW, int TR>
__global__ __launch_bounds__(NT, 8)
void fused_kernel(const float* __restrict__ ww,    // [B,W,M]
                  const float* __restrict__ fg,    // [B,R]
                  const float* __restrict__ rw,    // [B,R,M]
                  const float* __restrict__ prev,  // [B,M]
                  const float* __restrict__ wgt,   // [B,W]
                  float* __restrict__ out_usage,   // [B,M]
                  float* __restrict__ out_alloc,   // [B,W,M]
                  int B, int W, int R, int M)
{
    __shared__ u64   poolKey[POOLCAP];  // (~nnbits)<<16 | idx  (asc == nonusage desc)
    __shared__ float poolLg[POOLCAP];   // log2(ue_b) per pool element
    __shared__ u64   candKey[CAP];
    __shared__ float candLg[CAP];
    __shared__ u16   candPos[CAP];      // pool slot of candidate
    __shared__ u32   hC[NBINS];         // persistent across heads (incremental)
    __shared__ float mB[NBINS];         // per-bucket upper bound of log2(ue)
    __shared__ u32   tc[16];
    __shared__ float twv[16];
    __shared__ int   misc[6];           // [0]=pool cnt,[1]=xs,[2]=xc,[3]=pc,[4]=cand cnt

    const int Wl = TW > 0 ? TW : W;
    const int Rl = TR > 0 ? TR : R;
    const int b = blockIdx.x;
    const int t = threadIdx.x;
    const int lane = t & 63;
    const int wid = t >> 6;

    const float C1 = (float)(1.0 - 1e-6);
    const float CE = 1e-6f;
    const size_t rowOff = (size_t)b * M;

    // init hist + mass-bound table (once)
    if (t < NBINS) {
        hC[t] = 0u;
        const int v = NBINS - 1 - t;          // (e<<4)|sub
        const int e = v >> 4;
        const u32 sub = (u32)(v & 15);
        const int sh = e >= 4 ? e - 4 : 0;
        u64 dhi64 = ((u64)(17u + sub) << sh) + 1u;   // safe upper bound of d in bucket
        u32 dhi = dhi64 > 0x3F800000ull ? 0x3F800000u : (u32)dhi64;
        const float nnlo = __uint_as_float(0x3F800000u - dhi);
        float ueub = 1.0f - nnlo;
        ueub = ueub < 1e-38f ? 1e-38f : (ueub > 0.9999999f ? 0.9999999f : ueub);
        mB[t] = __log2f(ueub);                // >= log2(ue) for bucket members
    }
    if (t == 0) { misc[0] = 0; misc[3] = NBINS; }
    __syncthreads();

    // ---------------- Phase S: streaming + inline bucket hist ----------------
    // usage = (prev + (1-prev)*(1-prod_w(1-ww))) * prod_r(1-fg*rw), ref f32 op order
    {
        float frs[TR > 0 ? TR : 8];
        #pragma unroll
        for (int r = 0; r < Rl; ++r) frs[r] = fg[(size_t)b * Rl + r];

        const float4 z = make_float4(0.f, 0.f, 0.f, 0.f);
        for (int m = t * 4; m < M; m += NT * 4) {
            const float4 pv = *(const float4*)(prev + rowOff + m);
            float pr0 = 1.f, pr1 = 1.f, pr2 = 1.f, pr3 = 1.f;
            #pragma unroll
            for (int w = 0; w < Wl; ++w) {
                const float4 a = *(const float4*)(ww + ((size_t)b * Wl + w) * M + m);
                pr0 *= (1.0f - a.x); pr1 *= (1.0f - a.y);
                pr2 *= (1.0f - a.z); pr3 *= (1.0f - a.w);
            }
            float u0 = pv.x + (1.0f - pv.x) * (1.0f - pr0);
            float u1 = pv.y + (1.0f - pv.y) * (1.0f - pr1);
            float u2 = pv.z + (1.0f - pv.z) * (1.0f - pr2);
            float u3 = pv.w + (1.0f - pv.w) * (1.0f - pr3);
            float f0 = 1.f, f1 = 1.f, f2 = 1.f, f3 = 1.f;
            #pragma unroll
            for (int r = 0; r < Rl; ++r) {
                const float fr = frs[r];
                const float4 a = *(const float4*)(rw + ((size_t)b * Rl + r) * M + m);
                f0 *= (1.0f - fr * a.x); f1 *= (1.0f - fr * a.y);
                f2 *= (1.0f - fr * a.z); f3 *= (1.0f - fr * a.w);
            }
            float4 uo;
            uo.x = u0 * f0; uo.y = u1 * f1; uo.z = u2 * f2; uo.w = u3 * f3;
            *(float4*)(out_usage + rowOff + m) = uo;    // regular store: keep L2-hot
            #pragma unroll
            for (int w = 0; w < Wl; ++w)
                nt_store4(out_alloc + ((size_t)b * Wl + w) * M + m, z);
            const float ua[4] = {uo.x, uo.y, uo.z, uo.w};
            #pragma unroll
            for (int j = 0; j < 4; ++j) {
                const float nn = 1.0f - (CE + C1 * ua[j]);
                atomicAdd(&hC[bucket_of(__float_as_uint(nn))], 1u);
            }
        }
    }
    __syncthreads();   // drains vmcnt: usage visible in L2; hist complete

    // ---------------- Pool cut: min x with suffix-count <= POOLCAP ----------------
    {
        const bool act = (t < NBINS);
        u32 sc = 0; int x = 0;
        if (act) {
            x = NBINS - 1 - t;
            sc = hC[x];
            #pragma unroll
            for (int off = 1; off < 64; off <<= 1) {
                const u32 oc = __shfl_up(sc, off);
                if (lane >= off) sc += oc;
            }
            if (lane == 63) tc[wid] = sc;
        }
        __syncthreads();
        if (act) {
            u32 ac = 0;
            for (int q = 0; q < wid; ++q) ac += tc[q];
            sc += ac;
            if (sc <= (u32)POOLCAP) atomicMin(&misc[3], x);
        }
    }
    __syncthreads();
    const int pc = misc[3];

    // ---------------- Pool build: one L2-hot re-read of this row's usage ----------------
    for (int m = t * 4; m < M; m += NT * 4) {
        const float4 uu = *(const float4*)(out_usage + rowOff + m);
        const float ua[4] = {uu.x, uu.y, uu.z, uu.w};
        #pragma unroll
        for (int j = 0; j < 4; ++j) {
            const float ue = CE + C1 * ua[j];
            const float nn = 1.0f - ue;
            const u32 nnbits = __float_as_uint(nn);
            const int bkt = bucket_of(nnbits);
            const bool pred = (bkt >= pc) && (pc < NBINS);
            const u64 mask = __ballot(pred);
            const int cnt = __popcll(mask);
            if (cnt) {
                int base = 0;
                if (lane == 0) base = atomicAdd(&misc[0], cnt);
                base = __shfl(base, 0);
                if (pred) {
                    const int pos = base + __popcll(mask & ((1ull << lane) - 1));
                    if (pos < POOLCAP) {
                        poolKey[pos] = (((u64)(~nnbits)) << 16) | (u64)(u32)(m + j);
                        poolLg[pos] = __log2f(ue);
                    }
                }
            }
        }
    }
    __syncthreads();
    int P = misc[0]; if (P > POOLCAP) P = POOLCAP;

    // ---------------- Phase H: per write head (pool-only) ----------------
    for (int i = 0; i < Wl; ++i) {
        const float wgi = wgt[(size_t)b * Wl + i];
        float* orow = out_alloc + ((size_t)b * Wl + i) * M;

        if (t == 0) { misc[4] = 0; misc[1] = -1; misc[2] = NBINS; }
        __syncthreads();   // orders prior-head pool/hist updates

        // suffix scan over persistent hist: count + bounded mass (hC[x]*mB[x]);
        // gated to x >= pc (head cuts provably never fall below pc)
        {
            const bool act = (t < NBINS);
            u32 sc = 0; float sw = 0.f; int x = 0;
            if (act) {
                x = NBINS - 1 - t;
                const u32 c = hC[x];
                sc = c;
                sw = mB[x] * (float)c;
                #pragma unroll
                for (int off = 1; off < 64; off <<= 1) {
                    const u32  oc = __shfl_up(sc, off);
                    const float ow = __shfl_up(sw, off);
                    if (lane >= off) { sc += oc; sw += ow; }
                }
                if (lane == 63) { tc[wid] = sc; twv[wid] = sw; }
            }
            __syncthreads();
            if (act) {
                u32 ac = 0; float aw = 0.f;
                for (int q = 0; q < wid; ++q) { ac += tc[q]; aw += twv[q]; }
                sc += ac; sw += aw;
                if (x >= pc) {
                    if (sw <= LOG_CUT) atomicMax(&misc[1], x);   // enough log-mass
                    if (sc <= (u32)CAP) atomicMin(&misc[2], x);  // within count cap
                }
            }
        }
        __syncthreads();
        const int xs = misc[1];
        const int xc = misc[2];
        const int cut = (xs > xc) ? xs : xc;

        // compact candidates from the POOL (2 iters), wave-aggregated counter
        for (int p = t; p < P; p += NT) {
            const u64 key = poolKey[p];
            const u32 nnbits = ~((u32)(key >> 16));
            const int bkt = bucket_of(nnbits);
            const bool pred = (bkt >= cut) && (cut < NBINS);
            const u64 mask = __ballot(pred);
            const int cnt = __popcll(mask);
            if (cnt) {
                int base = 0;
                if (lane == 0) base = atomicAdd(&misc[4], cnt);
                base = __shfl(base, 0);
                if (pred) {
                    const int pos = base + __popcll(mask & ((1ull << lane) - 1));
                    if (pos < CAP) {
                        candKey[pos] = key;
                        candLg[pos] = poolLg[p];
                        candPos[pos] = (u16)p;
                    }
                }
            }
        }
        __syncthreads();
        int K = misc[4]; if (K > CAP) K = CAP;

        // pairwise rank: S = sum log2(ue_k) over strictly-smaller keys;
        // alloc = nn * exp2(S); update pool + incremental hist (skip on last head)
        if (t < K) {
            const u64 mykey = candKey[t];
            float S = 0.0f;
            #pragma unroll 4
            for (int k = 0; k < K; ++k) {
                const u64 kk = candKey[k];   // LDS broadcast
                const float lg = candLg[k];
                if (kk < mykey) S += lg;
            }
            const u32 nnbits = ~((u32)(mykey >> 16));
            const float nn = __uint_as_float(nnbits);
            const int idx = (int)(mykey & 0xFFFFull);
            const float al = nn * __builtin_exp2f(S);
            if (al != 0.0f) {
                orow[idx] = al;                          // row pre-zeroed in phase S
                if (i + 1 < Wl) {
                    const float u0v = 1.0f - (nn + CE) / C1;   // not needed exactly; use below
                    // exact ref update needs original u: recover via ue_b = 1-nn
                    // u_new = u + (1-u)*wg*al where u is the CURRENT usage value.
                    // Current usage u satisfies ue = CE + C1*u = 1-nn  =>  u = (1-nn-CE)/C1
                    const float ucur = (1.0f - nn - CE) / C1;
                    const float unew = ucur + ((1.0f - ucur) * wgi) * al;
                    const float nn2 = 1.0f - (CE + C1 * unew);
                    const u32 nn2bits = __float_as_uint(nn2);
                    const int p = (int)candPos[t];
                    poolKey[p] = (((u64)(~nn2bits)) << 16) | (u64)(u32)idx;
                    poolLg[p] = __log2f(1.0f - nn2);
                    const int bold = bucket_of(nnbits);
                    const int bnew = bucket_of(nn2bits);
                    if (bnew != bold) {
                        atomicSub(&hC[bold], 1u);
                        atomicAdd(&hC[bnew], 1u);
                    }
                }
            }
        }
        __syncthreads();
    }
}

extern "C" void kernel_launch(void* const* d_in, const int* in_sizes, int n_in,
                              void* d_out, int out_size, void* d_ws, size_t ws_size,
                              hipStream_t stream) {
    const float* ww   = (const float*)d_in[0];
    const float* fg   = (const float*)d_in[1];
    const float* rw   = (const float*)d_in[2];
    const float* prev = (const float*)d_in[3];
    const float* wgt  = (const float*)d_in[4];
    const int BWM = in_sizes[0];
    const int BR  = in_sizes[1];
    const int BM  = in_sizes[3];
    const int BW  = in_sizes[4];
    const int M = BWM / BW;
    const int B = BM / M;
    const int W = BW / B;
    const int R = BR / B;

    float* out_usage = (float*)d_out;
    float* out_alloc = out_usage + (size_t)BM;

    if (W == 4 && R == 8) {
        hipLaunchKernelGGL((fused_kernel<4, 8>), dim3(B), dim3(NT), 0, stream,
                           ww, fg, rw, prev, wgt, out_usage, out_alloc, B, W, R, M);
    } else {
        hipLaunchKernelGGL((fused_kernel<0, 0>), dim3(B), dim3(NT), 0, stream,
                           ww, fg, rw, prev, wgt, out_usage, out_alloc, B, W, R, M);
    }
}